// Round 15
// baseline (201.688 us; speedup 1.0000x reference)
//
#include <hip/hip_runtime.h>
#include <stdint.h>

// ---------------- constants ----------------
constexpr int Bq = 8, Nn = 1025, Dd = 768, Hh = 12, HDd = 64, Pp = 1024;
constexpr int NP = 1088;              // padded N = 17*64
constexpr int MROWS = Bq * Nn;        // 8200
constexpr float EPSI = 1e-6f;

typedef __attribute__((ext_vector_type(8))) short bfrag;    // 8 bf16 = 4 VGPR
typedef __attribute__((ext_vector_type(4))) short bfrag4;   // 4 bf16 = 2 VGPR
typedef __attribute__((ext_vector_type(4))) float ffrag;    // 4 f32
typedef __attribute__((ext_vector_type(4))) float f4;
typedef __attribute__((ext_vector_type(4))) unsigned short us4;

#define MFMA16(a, b, c) __builtin_amdgcn_mfma_f32_16x16x32_bf16((a), (b), (c), 0, 0, 0)

// 16x16x16 bf16 MFMA: A/B = 4 bf16 (2 VGPR). C layout identical to x32.
__device__ __forceinline__ ffrag MFMA16K16(bfrag4 a, bfrag4 b, ffrag c) {
#if __has_builtin(__builtin_amdgcn_mfma_f32_16x16x16bf16_1k)
  return __builtin_amdgcn_mfma_f32_16x16x16bf16_1k(a, b, c, 0, 0, 0);
#else
  asm volatile("v_mfma_f32_16x16x16_bf16 %0, %1, %2, %0" : "+v"(c) : "v"(a), "v"(b));
  return c;
#endif
}

#if __has_builtin(__builtin_amdgcn_exp2f)
#define EXP2(x) __builtin_amdgcn_exp2f(x)
#else
#define EXP2(x) exp2f(x)
#endif

__device__ __forceinline__ unsigned short f2bf(float f) {
  union { float f; uint32_t u; } v{f};
  uint32_t u = v.u;
  return (unsigned short)((u + 0x7fffu + ((u >> 16) & 1u)) >> 16);  // RNE
}
__device__ __forceinline__ float bf2f(unsigned short s) {
  union { uint32_t u; float f; } v; v.u = ((uint32_t)s) << 16; return v.f;
}
// pack 2 f32 -> 2 bf16 in one u32 (lo = a, hi = b), RNE
__device__ __forceinline__ uint32_t pkbf(float a, float b) {
  uint32_t r;
  asm("v_cvt_pk_bf16_f32 %0, %1, %2" : "=v"(r) : "v"(a), "v"(b));
  return r;
}

// async global -> LDS, 16B per lane. LDS dest must be wave-uniform base + lane*16.
__device__ __forceinline__ void gload16(const void* g, void* l) {
  __builtin_amdgcn_global_load_lds((const __attribute__((address_space(1))) unsigned int*)g,
                                   (__attribute__((address_space(3))) unsigned int*)l, 16, 0, 0);
}

// ---------------- fused prologue: conv3 | padzero | pw by block range (R13 config) ----------------
__global__ __launch_bounds__(256) void prep_kernel(const float* __restrict__ s0, unsigned short* __restrict__ d0, int n0,
                                                   const float* __restrict__ s1, unsigned short* __restrict__ d1, int n1,
                                                   const float* __restrict__ s2, unsigned short* __restrict__ d2, int n2,
                                                   unsigned short* __restrict__ Qo,
                                                   unsigned short* __restrict__ Ko,
                                                   unsigned short* __restrict__ Vo,
                                                   const float* __restrict__ tr, float* __restrict__ pw) {
  __shared__ float red[256];
  int bid = blockIdx.x;
  if (bid < 2048) {
    int idx = bid * 256 + threadIdx.x;
    int stride = 2048 * 256;
    int ntot = n0 + n1 + n2;
    for (int i = idx; i < ntot; i += stride) {
      const float* src; unsigned short* dst; int k;
      if (i < n0) { src = s0; dst = d0; k = i; }
      else if (i < n0 + n1) { src = s1; dst = d1; k = i - n0; }
      else { src = s2; dst = d2; k = i - n0 - n1; }
      f4 v = ((const f4*)src)[k];
      us4 o; o[0] = f2bf(v[0]); o[1] = f2bf(v[1]); o[2] = f2bf(v[2]); o[3] = f2bf(v[3]);
      ((us4*)dst)[k] = o;
    }
  } else if (bid < 2144) {
    int bh = bid - 2048;  // 0..95
    unsigned short* qp = Qo + ((size_t)bh * NP + Nn) * 64;
    unsigned short* kp = Ko + ((size_t)bh * NP + Nn) * 64;
    for (int idx = threadIdx.x; idx < (NP - Nn) * 64; idx += 256) { qp[idx] = 0; kp[idx] = 0; }
    unsigned short* vp = Vo + (size_t)bh * 64 * NP;
    for (int idx = threadIdx.x; idx < 64 * (NP - Nn); idx += 256) {
      int d = idx / (NP - Nn), j = Nn + (idx - d * (NP - Nn));
      vp[(size_t)d * NP + j] = 0;
    }
  } else {
    int b = bid - 2144;  // 0..7
    float s = 0.f;
    for (int j = threadIdx.x; j < Pp; j += 256) s += tr[b * Pp + j];
    red[threadIdx.x] = s; __syncthreads();
    for (int o = 128; o > 0; o >>= 1) { if (threadIdx.x < o) red[threadIdx.x] += red[threadIdx.x + o]; __syncthreads(); }
    float inv = 1.f / (red[0] + EPSI);
    for (int j = threadIdx.x; j < Pp; j += 256) pw[b * Pp + j] = tr[b * Pp + j] * inv;
  }
}

// ---------------- mask bf16 [B][NP][NP], zero padded; vectorized f4 graph loads ----------------
__global__ __launch_bounds__(256) void mask_kernel(const float* __restrict__ graph,
                                                   const float* __restrict__ pw,
                                                   unsigned short* __restrict__ mask) {
  int i = blockIdx.x, b = blockIdx.y;
  int t = threadIdx.x;
  unsigned short* mrow = mask + ((size_t)b * NP + i) * NP;
  if (i >= Nn) {
    for (int j = t; j < NP; j += 256) mrow[j] = 0;
    return;
  }
  const float* src = (i == 0) ? (pw + b * Pp) : (graph + ((size_t)b * Pp + (i - 1)) * Pp);
  f4 v = ((const f4*)src)[t];
  int j = 1 + 4 * t;
  mrow[j]     = f2bf(v[0]);
  mrow[j + 1] = f2bf(v[1]);
  mrow[j + 2] = f2bf(v[2]);
  mrow[j + 3] = f2bf(v[3]);
  if (t == 0) mrow[0] = (i == 0) ? f2bf(1.f) : f2bf(pw[b * Pp + i - 1]);
  for (int jj = Nn + t; jj < NP; jj += 256) mrow[jj] = 0;
}

// ---------------- GEMM core: 128x128 tile, BK=64, K=768, bf16 MFMA ----------------
// 2-phase double-buffered pipeline (R8/R10 proven). R15 edit: ds_read fragment loads
// issued BEFORE the stage of tile t+1 — their lgkm latency overlaps the 8-gload issue
// sequence instead of serializing after it. Sync structure unchanged.
__device__ __forceinline__ void gemm_main(const unsigned short* __restrict__ A, int rowA0, int rowAmax,
                                          const unsigned short* __restrict__ Bw, int rowB0,
                                          uint4* lds, ffrag acc[4][4], int tid) {
  const int l = tid & 63, lm = l & 15, lg = l >> 4, w = tid >> 6, wr = w >> 1, wc = w & 1;
  const unsigned short* aS[4]; const unsigned short* bS[4];
#pragma unroll
  for (int q = 0; q < 4; q++) {
    int c = tid + 256 * q, r = c >> 3, p = c & 7, g = p ^ (r & 7);
    int ra = rowA0 + r; if (ra > rowAmax) ra = rowAmax;
    aS[q] = A + (size_t)ra * 768 + 8 * g;
    bS[q] = Bw + (size_t)(rowB0 + r) * 768 + 8 * g;
  }
  uint4* buf0 = lds;
  uint4* buf1 = lds + 2048;
#pragma unroll
  for (int q = 0; q < 4; q++) {
    gload16(aS[q], buf0 + tid + 256 * q);
    gload16(bS[q], buf0 + 1024 + tid + 256 * q);
    aS[q] += 64; bS[q] += 64;
  }
  asm volatile("s_waitcnt vmcnt(0)" ::: "memory");
  __builtin_amdgcn_sched_barrier(0);
  __builtin_amdgcn_s_barrier();
#pragma unroll 1
  for (int kt = 0; kt < 12; kt++) {
    uint4* cur = (kt & 1) ? buf1 : buf0;
    uint4* nxt = (kt & 1) ? buf0 : buf1;
    const bfrag* LA = (const bfrag*)cur;
    const bfrag* LB = (const bfrag*)(cur + 1024);
    // ds_reads FIRST: lgkm latency overlaps the stage-issue below
    bfrag af[4][2], bf_[4][2];
#pragma unroll
    for (int am = 0; am < 4; am++) {
      int row = wr * 64 + am * 16 + lm;
      af[am][0] = LA[row * 8 + ((0 + lg) ^ (row & 7))];
      af[am][1] = LA[row * 8 + ((4 + lg) ^ (row & 7))];
    }
#pragma unroll
    for (int an = 0; an < 4; an++) {
      int row = wc * 64 + an * 16 + lm;
      bf_[an][0] = LB[row * 8 + ((0 + lg) ^ (row & 7))];
      bf_[an][1] = LB[row * 8 + ((4 + lg) ^ (row & 7))];
    }
    if (kt < 11) {
#pragma unroll
      for (int q = 0; q < 4; q++) {
        gload16(aS[q], nxt + tid + 256 * q);
        gload16(bS[q], nxt + 1024 + tid + 256 * q);
        aS[q] += 64; bS[q] += 64;
      }
    }
#pragma unroll
    for (int am = 0; am < 4; am++)
#pragma unroll
      for (int an = 0; an < 4; an++) {
        acc[am][an] = MFMA16(af[am][0], bf_[an][0], acc[am][an]);
        acc[am][an] = MFMA16(af[am][1], bf_[an][1], acc[am][an]);
      }
    asm volatile("s_waitcnt vmcnt(0)" ::: "memory");
    __builtin_amdgcn_sched_barrier(0);
    __builtin_amdgcn_s_barrier();
  }
}

// bijective XCD-chunked mapping (m204)
__device__ __forceinline__ int xcd_chunk_map(int orig, int nwg) {
  int qq = nwg >> 3, rr = nwg & 7;
  int xcd = orig & 7, idx = orig >> 3;
  int base = (xcd < rr) ? xcd * (qq + 1) : rr * (qq + 1) + (xcd - rr) * qq;
  return base + idx;
}

// ---------------- kernel 1: QKV GEMM + scatter epilogue ----------------
__global__ __launch_bounds__(256) void qkv_gemm_kernel(const unsigned short* __restrict__ X,
                                                       const unsigned short* __restrict__ W,
                                                       const float* __restrict__ bias,
                                                       unsigned short* __restrict__ Qo,
                                                       unsigned short* __restrict__ Ko,
                                                       unsigned short* __restrict__ Vo) {
  __shared__ uint4 lds[4096];
  int tid = threadIdx.x;
  int wg = xcd_chunk_map(blockIdx.x, 65 * 18);
  int xt = wg / 18, yt = wg - 18 * xt;
  ffrag zero4 = {0.f, 0.f, 0.f, 0.f};
  ffrag acc[4][4];
#pragma unroll
  for (int i = 0; i < 4; i++)
#pragma unroll
    for (int j = 0; j < 4; j++) acc[i][j] = zero4;
  gemm_main(X, xt * 128, MROWS - 1, W, yt * 128, lds, acc, tid);
  const int l = tid & 63, lm = l & 15, lg = l >> 4, w = tid >> 6, wr = w >> 1, wc = w & 1;
#pragma unroll
  for (int an = 0; an < 4; an++) {
    int gc = yt * 128 + wc * 64 + an * 16 + lm;
    int which = gc / 768, rr = gc - which * 768, h = rr >> 6, hd = rr & 63;
    float bv = bias[gc];
#pragma unroll
    for (int am = 0; am < 4; am++) {
      int grb = xt * 128 + wr * 64 + am * 16 + 4 * lg;
#pragma unroll
      for (int r = 0; r < 4; r++) {
        int gr = grb + r;
        if (gr >= MROWS) continue;
        int b = gr / Nn, i = gr - b * Nn;
        size_t bh = (size_t)(b * Hh + h);
        float v = acc[am][an][r] + bv;
        // Q prescale folds softmax scale AND log2(e): 0.125 * 1.44269504
        if (which == 0)      Qo[(bh * NP + i) * 64 + hd] = f2bf(v * 0.18033688f);
        else if (which == 1) Ko[(bh * NP + i) * 64 + hd] = f2bf(v);
        else                 Vo[(bh * 64 + hd) * NP + i] = f2bf(v);           // V transposed
      }
    }
  }
}

// ---------------- kernel 3: proj GEMM + bias -> fp32 out ----------------
__global__ __launch_bounds__(256) void proj_gemm_kernel(const unsigned short* __restrict__ A,
                                                        const unsigned short* __restrict__ W,
                                                        const float* __restrict__ bias,
                                                        float* __restrict__ out) {
  __shared__ uint4 lds[4096];
  int tid = threadIdx.x;
  int wg = xcd_chunk_map(blockIdx.x, 65 * 6);
  int xt = wg / 6, yt = wg - 6 * xt;
  ffrag zero4 = {0.f, 0.f, 0.f, 0.f};
  ffrag acc[4][4];
#pragma unroll
  for (int i = 0; i < 4; i++)
#pragma unroll
    for (int j = 0; j < 4; j++) acc[i][j] = zero4;
  gemm_main(A, xt * 128, MROWS - 1, W, yt * 128, lds, acc, tid);
  const int l = tid & 63, lm = l & 15, lg = l >> 4, w = tid >> 6, wr = w >> 1, wc = w & 1;
#pragma unroll
  for (int an = 0; an < 4; an++) {
    int gc = yt * 128 + wc * 64 + an * 16 + lm;
    float bv = bias[gc];
#pragma unroll
    for (int am = 0; am < 4; am++) {
      int grb = xt * 128 + wr * 64 + am * 16 + 4 * lg;
#pragma unroll
      for (int r = 0; r < 4; r++) {
        int gr = grb + r;
        if (gr >= MROWS) continue;
        out[(size_t)gr * 768 + gc] = acc[am][an][r] + bv;
      }
    }
  }
}

// ---------------- kernel 2: fused masked attention, register-resident P (R11/R13) ----------------
__global__ __launch_bounds__(256) void attn_kernel(const unsigned short* __restrict__ Qg,
                                                   const unsigned short* __restrict__ Kg,
                                                   const unsigned short* __restrict__ Vg,
                                                   const unsigned short* __restrict__ Mg,
                                                   unsigned short* __restrict__ Og) {
  __shared__ uint4 smem[2048];  // dbuf x (K 8KB | V 8KB) = 32KB
  int tid = threadIdx.x, w = tid >> 6, l = tid & 63, lm = l & 15, lg = l >> 4;
  int bx = blockIdx.x;
  int b = bx & 7, t5 = bx >> 3;        // grid 864 = 8 * (12*9)
  int h = t5 % 12, ib = t5 / 12;       // ib 0..8, 128 q-rows each
  size_t bh = (size_t)(b * Hh + h);
  const unsigned short* Qb = Qg + bh * NP * 64;
  const unsigned short* Kb = Kg + bh * NP * 64;
  const unsigned short* Vb = Vg + bh * 64 * NP;
  int i0a = ib * 128 + w * 16;
  int i0b = i0a + 64;
  int irowa = i0a + lm; if (irowa > NP - 1) irowa = NP - 1;   // clamped rows are zero-padded
  int irowb = i0b + lm; if (irowb > NP - 1) irowb = NP - 1;
  const unsigned short* Mrowa = Mg + (size_t)b * NP * NP + (size_t)irowa * NP;
  const unsigned short* Mrowb = Mg + (size_t)b * NP * NP + (size_t)irowb * NP;

  bfrag qa0 = *(const bfrag*)(Qb + (size_t)irowa * 64 + 8 * lg);
  bfrag qa1 = *(const bfrag*)(Qb + (size_t)irowa * 64 + 32 + 8 * lg);
  bfrag qb0 = *(const bfrag*)(Qb + (size_t)irowb * 64 + 8 * lg);
  bfrag qb1 = *(const bfrag*)(Qb + (size_t)irowb * 64 + 32 + 8 * lg);

  ffrag zero4 = {0.f, 0.f, 0.f, 0.f};
  ffrag oaccA[4] = {zero4, zero4, zero4, zero4};
  ffrag oaccB[4] = {zero4, zero4, zero4, zero4};
  float TpA = 0.f, TpB = 0.f;

  // staging (pre-swizzled global addr, linear LDS dest)
  int rS = tid >> 3, pS = tid & 7;
  int rS2 = rS + 32;
  const unsigned short* kS0 = Kb + (size_t)rS * 64 + 8 * (pS ^ (rS & 7));
  const unsigned short* kS1 = Kb + (size_t)rS2 * 64 + 8 * (pS ^ (rS2 & 7));
  const unsigned short* vS0 = Vb + (size_t)rS * NP + 8 * (pS ^ (rS & 7));
  const unsigned short* vS1 = Vb + (size_t)rS2 * NP + 8 * (pS ^ (rS2 & 7));

  // prologue: stage tile 0 into buffer 0
  gload16(kS0, smem + tid);
  gload16(kS1, smem + tid + 256);
  gload16(vS0, smem + 512 + tid);
  gload16(vS1, smem + 512 + tid + 256);
  asm volatile("s_waitcnt vmcnt(0)" ::: "memory");
  __builtin_amdgcn_sched_barrier(0);
  __builtin_amdgcn_s_barrier();

#pragma unroll 1
  for (int t = 0; t < 17; t++) {
    int cb = (t & 1) << 10;   // current buffer: 1024 uint4 (K 512 | V 512)
    int j0 = t * 64;
    // mask loads FIRST: their mid-tile wait then leaves staging(t+1) in flight
    us4 mvA[4], mvB[4];
#pragma unroll
    for (int jm = 0; jm < 4; jm++) {
      mvA[jm] = *(const us4*)(Mrowa + j0 + 16 * jm + 4 * lg);
      mvB[jm] = *(const us4*)(Mrowb + j0 + 16 * jm + 4 * lg);
    }
    __builtin_amdgcn_sched_barrier(0);
    if (t < 16) {
      int nb = ((t + 1) & 1) << 10;
      size_t ko = (size_t)(t + 1) * 4096;   // K advances 64 rows * 64 elems
      int vo = (t + 1) * 64;                // V^T advances 64 columns
      gload16(kS0 + ko, smem + nb + tid);
      gload16(kS1 + ko, smem + nb + tid + 256);
      gload16(vS0 + vo, smem + nb + 512 + tid);
      gload16(vS1 + vo, smem + nb + 512 + tid + 256);
    }
    __builtin_amdgcn_sched_barrier(0);
    const bfrag* LK = (const bfrag*)(smem + cb);
    const char*  LVc = (const char*)(smem + cb + 512);

    // --- K fragments (shared by both sub-blocks) ---
    bfrag ka[4], kb2[4];
#pragma unroll
    for (int jm = 0; jm < 4; jm++) {
      int row = jm * 16 + lm;
      ka[jm]  = LK[row * 8 + ((0 + lg) ^ (row & 7))];
      kb2[jm] = LK[row * 8 + ((4 + lg) ^ (row & 7))];
    }
    // --- QK^T both sub-blocks (16x16x32) ---
    ffrag sa[4], sb[4];
    __builtin_amdgcn_s_setprio(1);
#pragma unroll
    for (int jm = 0; jm < 4; jm++) {
      ffrag a = zero4;
      a = MFMA16(ka[jm], qa0, a);
      a = MFMA16(kb2[jm], qa1, a);
      sa[jm] = a;
      ffrag bb = zero4;
      bb = MFMA16(ka[jm], qb0, bb);
      bb = MFMA16(kb2[jm], qb1, bb);
      sb[jm] = bb;
    }
    __builtin_amdgcn_s_setprio(0);

    // --- V B-fragments for 16x16x16 PV (shared by a,b) ---
    bfrag4 vf[4][4];
#pragma unroll
    for (int jm = 0; jm < 4; jm++)
#pragma unroll
      for (int dm = 0; dm < 4; dm++) {
        int vrow = dm * 16 + lm;
        union { uint2 u; bfrag4 b; } cu;
        cu.u = *(const uint2*)(LVc + vrow * 128 +
                               ((((jm << 1) | (lg >> 1)) ^ (vrow & 7)) << 4) + 8 * (lg & 1));
        vf[jm][dm] = cu.b;
      }

    // --- softmax -> PV A-fragments, all in registers ---
    bfrag4 paA[4], paB[4];
#pragma unroll
    for (int jm = 0; jm < 4; jm++) {
      float p0 = EXP2(sa[jm][0]), p1 = EXP2(sa[jm][1]), p2 = EXP2(sa[jm][2]), p3 = EXP2(sa[jm][3]);
      float q0 = p0 * bf2f(mvA[jm][0]), q1 = p1 * bf2f(mvA[jm][1]);
      float q2 = p2 * bf2f(mvA[jm][2]), q3 = p3 * bf2f(mvA[jm][3]);
      TpA += (q0 + q1) + (q2 + q3);
      union { uint2 u; bfrag4 b; } cv;
      cv.u.x = pkbf(q0, q1); cv.u.y = pkbf(q2, q3);
      paA[jm] = cv.b;
    }
#pragma unroll
    for (int jm = 0; jm < 4; jm++) {
      float p0 = EXP2(sb[jm][0]), p1 = EXP2(sb[jm][1]), p2 = EXP2(sb[jm][2]), p3 = EXP2(sb[jm][3]);
      float q0 = p0 * bf2f(mvB[jm][0]), q1 = p1 * bf2f(mvB[jm][1]);
      float q2 = p2 * bf2f(mvB[jm][2]), q3 = p3 * bf2f(mvB[jm][3]);
      TpB += (q0 + q1) + (q2 + q3);
      union { uint2 u; bfrag4 b; } cv;
      cv.u.x = pkbf(q0, q1); cv.u.y = pkbf(q2, q3);
      paB[jm] = cv.b;
    }

    // --- PV: 16x16x16, pure register operands; a/b interleaved for ILP ---
    __builtin_amdgcn_s_setprio(1);
#pragma unroll
    for (int jm = 0; jm < 4; jm++)
#pragma unroll
      for (int dm = 0; dm < 4; dm++) {
        oaccA[dm] = MFMA16K16(paA[jm], vf[jm][dm], oaccA[dm]);
        oaccB[dm] = MFMA16K16(paB[jm], vf[jm][dm], oaccB[dm]);
      }
    __builtin_amdgcn_s_setprio(0);

    // next tile's K/V landed; all waves done reading current buffers.
    asm volatile("s_waitcnt vmcnt(0)" ::: "memory");
    __builtin_amdgcn_sched_barrier(0);
    __builtin_amdgcn_s_barrier();
  }
  // --- finalize ---
  TpA += __shfl_xor(TpA, 16); TpA += __shfl_xor(TpA, 32);
  TpB += __shfl_xor(TpB, 16); TpB += __shfl_xor(TpB, 32);
  float dnA_row = 1.f / TpA;   // eps*Z term dropped (rel err ~2e-6)
  float dnB_row = 1.f / TpB;
  float dnA[4], dnB[4];
#pragma unroll
  for (int r = 0; r < 4; r++) { dnA[r] = __shfl(dnA_row, 4 * lg + r); dnB[r] = __shfl(dnB_row, 4 * lg + r); }
#pragma unroll
  for (int dm = 0; dm < 4; dm++)
#pragma unroll
    for (int r = 0; r < 4; r++) {
      int ia = i0a + 4 * lg + r;
      if (ia < Nn) Og[((size_t)(b * Nn + ia)) * Dd + h * 64 + dm * 16 + lm] = f2bf(oaccA[dm][r] * dnA[r]);
      int ibr = i0b + 4 * lg + r;
      if (ibr < Nn) Og[((size_t)(b * Nn + ibr)) * Dd + h * 64 + dm * 16 + lm] = f2bf(oaccB[dm][r] * dnB[r]);
    }
}

// ---------------- launch ----------------
extern "C" void kernel_launch(void* const* d_in, const int* in_sizes, int n_in,
                              void* d_out, int out_size, void* d_ws, size_t ws_size,
                              hipStream_t stream) {
  const float* x      = (const float*)d_in[0];
  const float* graph  = (const float*)d_in[1];
  const float* transf = (const float*)d_in[2];
  const float* Wqkv   = (const float*)d_in[3];
  const float* bqkv   = (const float*)d_in[4];
  const float* Wproj  = (const float*)d_in[5];
  const float* bproj  = (const float*)d_in[6];
  float* out = (float*)d_out;
  char* ws = (char*)d_ws;

  unsigned short* xbf  = (unsigned short*)(ws + 0);                 // 12,595,200 (also attn_out)
  unsigned short* wqb  = (unsigned short*)(ws + 12595200);          //  3,538,944
  unsigned short* wpb  = (unsigned short*)(ws + 16134144);          //  1,179,648
  unsigned short* Qb   = (unsigned short*)(ws + 17313792);          // 13,369,344
  unsigned short* Kb   = (unsigned short*)(ws + 30683136);          // 13,369,344
  unsigned short* Vb   = (unsigned short*)(ws + 44052480);          // 13,369,344
  float*          pw   = (float*)(ws + 57421824);                   //     32,768
  unsigned short* mask = (unsigned short*)(ws + 57454592);          // 18,939,904
  unsigned short* aob  = xbf;  // attention output bf16 [8200][768]

  prep_kernel<<<2152, 256, 0, stream>>>(x, xbf, (MROWS * Dd) / 4,
                                        Wqkv, wqb, (3 * Dd * Dd) / 4,
                                        Wproj, wpb, (Dd * Dd) / 4,
                                        Qb, Kb, Vb, transf, pw);
  mask_kernel<<<dim3(NP, Bq), 256, 0, stream>>>(graph, pw, mask);
  qkv_gemm_kernel<<<65 * 18, 256, 0, stream>>>(xbf, wqb, bqkv, Qb, Kb, Vb);
  attn_kernel<<<864, 256, 0, stream>>>(Qb, Kb, Vb, mask, aob);
  proj_gemm_kernel<<<65 * 6, 256, 0, stream>>>(aob, wpb, bproj, out);
}

// Round 16
// 194.840 us; speedup vs baseline: 1.0351x; 1.0351x over previous
//
#include <hip/hip_runtime.h>
#include <stdint.h>

// ---------------- constants ----------------
constexpr int Bq = 8, Nn = 1025, Dd = 768, Hh = 12, HDd = 64, Pp = 1024;
constexpr int NP = 1088;              // padded N = 17*64
constexpr int MROWS = Bq * Nn;        // 8200
constexpr float EPSI = 1e-6f;

typedef __attribute__((ext_vector_type(8))) short bfrag;    // 8 bf16 = 4 VGPR
typedef __attribute__((ext_vector_type(4))) short bfrag4;   // 4 bf16 = 2 VGPR
typedef __attribute__((ext_vector_type(4))) float ffrag;    // 4 f32
typedef __attribute__((ext_vector_type(4))) float f4;
typedef __attribute__((ext_vector_type(4))) unsigned short us4;

#define MFMA16(a, b, c) __builtin_amdgcn_mfma_f32_16x16x32_bf16((a), (b), (c), 0, 0, 0)

// 16x16x16 bf16 MFMA: A/B = 4 bf16 (2 VGPR). C layout identical to x32.
__device__ __forceinline__ ffrag MFMA16K16(bfrag4 a, bfrag4 b, ffrag c) {
#if __has_builtin(__builtin_amdgcn_mfma_f32_16x16x16bf16_1k)
  return __builtin_amdgcn_mfma_f32_16x16x16bf16_1k(a, b, c, 0, 0, 0);
#else
  asm volatile("v_mfma_f32_16x16x16_bf16 %0, %1, %2, %0" : "+v"(c) : "v"(a), "v"(b));
  return c;
#endif
}

#if __has_builtin(__builtin_amdgcn_exp2f)
#define EXP2(x) __builtin_amdgcn_exp2f(x)
#else
#define EXP2(x) exp2f(x)
#endif

__device__ __forceinline__ unsigned short f2bf(float f) {
  union { float f; uint32_t u; } v{f};
  uint32_t u = v.u;
  return (unsigned short)((u + 0x7fffu + ((u >> 16) & 1u)) >> 16);  // RNE
}
__device__ __forceinline__ float bf2f(unsigned short s) {
  union { uint32_t u; float f; } v; v.u = ((uint32_t)s) << 16; return v.f;
}
// pack 2 f32 -> 2 bf16 in one u32 (lo = a, hi = b), RNE
__device__ __forceinline__ uint32_t pkbf(float a, float b) {
  uint32_t r;
  asm("v_cvt_pk_bf16_f32 %0, %1, %2" : "=v"(r) : "v"(a), "v"(b));
  return r;
}

// async global -> LDS, 16B per lane. LDS dest must be wave-uniform base + lane*16.
__device__ __forceinline__ void gload16(const void* g, void* l) {
  __builtin_amdgcn_global_load_lds((const __attribute__((address_space(1))) unsigned int*)g,
                                   (__attribute__((address_space(3))) unsigned int*)l, 16, 0, 0);
}

// ---------------- fused prologue: conv3 | padzero | pw by block range (R13 config) ----------------
__global__ __launch_bounds__(256) void prep_kernel(const float* __restrict__ s0, unsigned short* __restrict__ d0, int n0,
                                                   const float* __restrict__ s1, unsigned short* __restrict__ d1, int n1,
                                                   const float* __restrict__ s2, unsigned short* __restrict__ d2, int n2,
                                                   unsigned short* __restrict__ Qo,
                                                   unsigned short* __restrict__ Ko,
                                                   unsigned short* __restrict__ Vo,
                                                   const float* __restrict__ tr, float* __restrict__ pw) {
  __shared__ float red[256];
  int bid = blockIdx.x;
  if (bid < 2048) {
    int idx = bid * 256 + threadIdx.x;
    int stride = 2048 * 256;
    int ntot = n0 + n1 + n2;
    for (int i = idx; i < ntot; i += stride) {
      const float* src; unsigned short* dst; int k;
      if (i < n0) { src = s0; dst = d0; k = i; }
      else if (i < n0 + n1) { src = s1; dst = d1; k = i - n0; }
      else { src = s2; dst = d2; k = i - n0 - n1; }
      f4 v = ((const f4*)src)[k];
      us4 o; o[0] = f2bf(v[0]); o[1] = f2bf(v[1]); o[2] = f2bf(v[2]); o[3] = f2bf(v[3]);
      ((us4*)dst)[k] = o;
    }
  } else if (bid < 2144) {
    int bh = bid - 2048;  // 0..95
    unsigned short* qp = Qo + ((size_t)bh * NP + Nn) * 64;
    unsigned short* kp = Ko + ((size_t)bh * NP + Nn) * 64;
    for (int idx = threadIdx.x; idx < (NP - Nn) * 64; idx += 256) { qp[idx] = 0; kp[idx] = 0; }
    unsigned short* vp = Vo + (size_t)bh * 64 * NP;
    for (int idx = threadIdx.x; idx < 64 * (NP - Nn); idx += 256) {
      int d = idx / (NP - Nn), j = Nn + (idx - d * (NP - Nn));
      vp[(size_t)d * NP + j] = 0;
    }
  } else {
    int b = bid - 2144;  // 0..7
    float s = 0.f;
    for (int j = threadIdx.x; j < Pp; j += 256) s += tr[b * Pp + j];
    red[threadIdx.x] = s; __syncthreads();
    for (int o = 128; o > 0; o >>= 1) { if (threadIdx.x < o) red[threadIdx.x] += red[threadIdx.x + o]; __syncthreads(); }
    float inv = 1.f / (red[0] + EPSI);
    for (int j = threadIdx.x; j < Pp; j += 256) pw[b * Pp + j] = tr[b * Pp + j] * inv;
  }
}

// ---------------- mask bf16 [B][NP][NP], zero padded; vectorized f4 graph loads ----------------
__global__ __launch_bounds__(256) void mask_kernel(const float* __restrict__ graph,
                                                   const float* __restrict__ pw,
                                                   unsigned short* __restrict__ mask) {
  int i = blockIdx.x, b = blockIdx.y;
  int t = threadIdx.x;
  unsigned short* mrow = mask + ((size_t)b * NP + i) * NP;
  if (i >= Nn) {
    for (int j = t; j < NP; j += 256) mrow[j] = 0;
    return;
  }
  const float* src = (i == 0) ? (pw + b * Pp) : (graph + ((size_t)b * Pp + (i - 1)) * Pp);
  f4 v = ((const f4*)src)[t];
  int j = 1 + 4 * t;
  mrow[j]     = f2bf(v[0]);
  mrow[j + 1] = f2bf(v[1]);
  mrow[j + 2] = f2bf(v[2]);
  mrow[j + 3] = f2bf(v[3]);
  if (t == 0) mrow[0] = (i == 0) ? f2bf(1.f) : f2bf(pw[b * Pp + i - 1]);
  for (int jj = Nn + t; jj < NP; jj += 256) mrow[jj] = 0;
}

// ---------------- GEMM core: 128x128 tile, BK=64, K=768, bf16 MFMA ----------------
// 2-phase double-buffered pipeline (R8/R10/R13 proven ordering): stage tile t+1 FIRST
// (gloads get the whole ds_read+MFMA window to land before the end-of-step vmcnt(0)),
// then ds_read fragments, then MFMAs. R15's ds_read-hoist variant regressed (+20us on
// qkv): delaying the stage issue re-exposes stage latency at the drain.
__device__ __forceinline__ void gemm_main(const unsigned short* __restrict__ A, int rowA0, int rowAmax,
                                          const unsigned short* __restrict__ Bw, int rowB0,
                                          uint4* lds, ffrag acc[4][4], int tid) {
  const int l = tid & 63, lm = l & 15, lg = l >> 4, w = tid >> 6, wr = w >> 1, wc = w & 1;
  const unsigned short* aS[4]; const unsigned short* bS[4];
#pragma unroll
  for (int q = 0; q < 4; q++) {
    int c = tid + 256 * q, r = c >> 3, p = c & 7, g = p ^ (r & 7);
    int ra = rowA0 + r; if (ra > rowAmax) ra = rowAmax;
    aS[q] = A + (size_t)ra * 768 + 8 * g;
    bS[q] = Bw + (size_t)(rowB0 + r) * 768 + 8 * g;
  }
  uint4* buf0 = lds;
  uint4* buf1 = lds + 2048;
#pragma unroll
  for (int q = 0; q < 4; q++) {
    gload16(aS[q], buf0 + tid + 256 * q);
    gload16(bS[q], buf0 + 1024 + tid + 256 * q);
    aS[q] += 64; bS[q] += 64;
  }
  asm volatile("s_waitcnt vmcnt(0)" ::: "memory");
  __builtin_amdgcn_sched_barrier(0);
  __builtin_amdgcn_s_barrier();
#pragma unroll 1
  for (int kt = 0; kt < 12; kt++) {
    uint4* cur = (kt & 1) ? buf1 : buf0;
    uint4* nxt = (kt & 1) ? buf0 : buf1;
    if (kt < 11) {
#pragma unroll
      for (int q = 0; q < 4; q++) {
        gload16(aS[q], nxt + tid + 256 * q);
        gload16(bS[q], nxt + 1024 + tid + 256 * q);
        aS[q] += 64; bS[q] += 64;
      }
    }
    const bfrag* LA = (const bfrag*)cur;
    const bfrag* LB = (const bfrag*)(cur + 1024);
    bfrag af[4][2], bf_[4][2];
#pragma unroll
    for (int am = 0; am < 4; am++) {
      int row = wr * 64 + am * 16 + lm;
      af[am][0] = LA[row * 8 + ((0 + lg) ^ (row & 7))];
      af[am][1] = LA[row * 8 + ((4 + lg) ^ (row & 7))];
    }
#pragma unroll
    for (int an = 0; an < 4; an++) {
      int row = wc * 64 + an * 16 + lm;
      bf_[an][0] = LB[row * 8 + ((0 + lg) ^ (row & 7))];
      bf_[an][1] = LB[row * 8 + ((4 + lg) ^ (row & 7))];
    }
#pragma unroll
    for (int am = 0; am < 4; am++)
#pragma unroll
      for (int an = 0; an < 4; an++) {
        acc[am][an] = MFMA16(af[am][0], bf_[an][0], acc[am][an]);
        acc[am][an] = MFMA16(af[am][1], bf_[an][1], acc[am][an]);
      }
    asm volatile("s_waitcnt vmcnt(0)" ::: "memory");
    __builtin_amdgcn_sched_barrier(0);
    __builtin_amdgcn_s_barrier();
  }
}

// bijective XCD-chunked mapping (m204)
__device__ __forceinline__ int xcd_chunk_map(int orig, int nwg) {
  int qq = nwg >> 3, rr = nwg & 7;
  int xcd = orig & 7, idx = orig >> 3;
  int base = (xcd < rr) ? xcd * (qq + 1) : rr * (qq + 1) + (xcd - rr) * qq;
  return base + idx;
}

// ---------------- kernel 1: QKV GEMM + scatter epilogue ----------------
__global__ __launch_bounds__(256) void qkv_gemm_kernel(const unsigned short* __restrict__ X,
                                                       const unsigned short* __restrict__ W,
                                                       const float* __restrict__ bias,
                                                       unsigned short* __restrict__ Qo,
                                                       unsigned short* __restrict__ Ko,
                                                       unsigned short* __restrict__ Vo) {
  __shared__ uint4 lds[4096];
  int tid = threadIdx.x;
  int wg = xcd_chunk_map(blockIdx.x, 65 * 18);
  int xt = wg / 18, yt = wg - 18 * xt;
  ffrag zero4 = {0.f, 0.f, 0.f, 0.f};
  ffrag acc[4][4];
#pragma unroll
  for (int i = 0; i < 4; i++)
#pragma unroll
    for (int j = 0; j < 4; j++) acc[i][j] = zero4;
  gemm_main(X, xt * 128, MROWS - 1, W, yt * 128, lds, acc, tid);
  const int l = tid & 63, lm = l & 15, lg = l >> 4, w = tid >> 6, wr = w >> 1, wc = w & 1;
#pragma unroll
  for (int an = 0; an < 4; an++) {
    int gc = yt * 128 + wc * 64 + an * 16 + lm;
    int which = gc / 768, rr = gc - which * 768, h = rr >> 6, hd = rr & 63;
    float bv = bias[gc];
#pragma unroll
    for (int am = 0; am < 4; am++) {
      int grb = xt * 128 + wr * 64 + am * 16 + 4 * lg;
#pragma unroll
      for (int r = 0; r < 4; r++) {
        int gr = grb + r;
        if (gr >= MROWS) continue;
        int b = gr / Nn, i = gr - b * Nn;
        size_t bh = (size_t)(b * Hh + h);
        float v = acc[am][an][r] + bv;
        // Q prescale folds softmax scale AND log2(e): 0.125 * 1.44269504
        if (which == 0)      Qo[(bh * NP + i) * 64 + hd] = f2bf(v * 0.18033688f);
        else if (which == 1) Ko[(bh * NP + i) * 64 + hd] = f2bf(v);
        else                 Vo[(bh * 64 + hd) * NP + i] = f2bf(v);           // V transposed
      }
    }
  }
}

// ---------------- kernel 3: proj GEMM + bias -> fp32 out ----------------
__global__ __launch_bounds__(256) void proj_gemm_kernel(const unsigned short* __restrict__ A,
                                                        const unsigned short* __restrict__ W,
                                                        const float* __restrict__ bias,
                                                        float* __restrict__ out) {
  __shared__ uint4 lds[4096];
  int tid = threadIdx.x;
  int wg = xcd_chunk_map(blockIdx.x, 65 * 6);
  int xt = wg / 6, yt = wg - 6 * xt;
  ffrag zero4 = {0.f, 0.f, 0.f, 0.f};
  ffrag acc[4][4];
#pragma unroll
  for (int i = 0; i < 4; i++)
#pragma unroll
    for (int j = 0; j < 4; j++) acc[i][j] = zero4;
  gemm_main(A, xt * 128, MROWS - 1, W, yt * 128, lds, acc, tid);
  const int l = tid & 63, lm = l & 15, lg = l >> 4, w = tid >> 6, wr = w >> 1, wc = w & 1;
#pragma unroll
  for (int an = 0; an < 4; an++) {
    int gc = yt * 128 + wc * 64 + an * 16 + lm;
    float bv = bias[gc];
#pragma unroll
    for (int am = 0; am < 4; am++) {
      int grb = xt * 128 + wr * 64 + am * 16 + 4 * lg;
#pragma unroll
      for (int r = 0; r < 4; r++) {
        int gr = grb + r;
        if (gr >= MROWS) continue;
        out[(size_t)gr * 768 + gc] = acc[am][an][r] + bv;
      }
    }
  }
}

// ---------------- kernel 2: fused masked attention, register-resident P (R11/R13) ----------------
__global__ __launch_bounds__(256) void attn_kernel(const unsigned short* __restrict__ Qg,
                                                   const unsigned short* __restrict__ Kg,
                                                   const unsigned short* __restrict__ Vg,
                                                   const unsigned short* __restrict__ Mg,
                                                   unsigned short* __restrict__ Og) {
  __shared__ uint4 smem[2048];  // dbuf x (K 8KB | V 8KB) = 32KB
  int tid = threadIdx.x, w = tid >> 6, l = tid & 63, lm = l & 15, lg = l >> 4;
  int bx = blockIdx.x;
  int b = bx & 7, t5 = bx >> 3;        // grid 864 = 8 * (12*9)
  int h = t5 % 12, ib = t5 / 12;       // ib 0..8, 128 q-rows each
  size_t bh = (size_t)(b * Hh + h);
  const unsigned short* Qb = Qg + bh * NP * 64;
  const unsigned short* Kb = Kg + bh * NP * 64;
  const unsigned short* Vb = Vg + bh * 64 * NP;
  int i0a = ib * 128 + w * 16;
  int i0b = i0a + 64;
  int irowa = i0a + lm; if (irowa > NP - 1) irowa = NP - 1;   // clamped rows are zero-padded
  int irowb = i0b + lm; if (irowb > NP - 1) irowb = NP - 1;
  const unsigned short* Mrowa = Mg + (size_t)b * NP * NP + (size_t)irowa * NP;
  const unsigned short* Mrowb = Mg + (size_t)b * NP * NP + (size_t)irowb * NP;

  bfrag qa0 = *(const bfrag*)(Qb + (size_t)irowa * 64 + 8 * lg);
  bfrag qa1 = *(const bfrag*)(Qb + (size_t)irowa * 64 + 32 + 8 * lg);
  bfrag qb0 = *(const bfrag*)(Qb + (size_t)irowb * 64 + 8 * lg);
  bfrag qb1 = *(const bfrag*)(Qb + (size_t)irowb * 64 + 32 + 8 * lg);

  ffrag zero4 = {0.f, 0.f, 0.f, 0.f};
  ffrag oaccA[4] = {zero4, zero4, zero4, zero4};
  ffrag oaccB[4] = {zero4, zero4, zero4, zero4};
  float TpA = 0.f, TpB = 0.f;

  // staging (pre-swizzled global addr, linear LDS dest)
  int rS = tid >> 3, pS = tid & 7;
  int rS2 = rS + 32;
  const unsigned short* kS0 = Kb + (size_t)rS * 64 + 8 * (pS ^ (rS & 7));
  const unsigned short* kS1 = Kb + (size_t)rS2 * 64 + 8 * (pS ^ (rS2 & 7));
  const unsigned short* vS0 = Vb + (size_t)rS * NP + 8 * (pS ^ (rS & 7));
  const unsigned short* vS1 = Vb + (size_t)rS2 * NP + 8 * (pS ^ (rS2 & 7));

  // prologue: stage tile 0 into buffer 0
  gload16(kS0, smem + tid);
  gload16(kS1, smem + tid + 256);
  gload16(vS0, smem + 512 + tid);
  gload16(vS1, smem + 512 + tid + 256);
  asm volatile("s_waitcnt vmcnt(0)" ::: "memory");
  __builtin_amdgcn_sched_barrier(0);
  __builtin_amdgcn_s_barrier();

#pragma unroll 1
  for (int t = 0; t < 17; t++) {
    int cb = (t & 1) << 10;   // current buffer: 1024 uint4 (K 512 | V 512)
    int j0 = t * 64;
    // mask loads FIRST: their mid-tile wait then leaves staging(t+1) in flight
    us4 mvA[4], mvB[4];
#pragma unroll
    for (int jm = 0; jm < 4; jm++) {
      mvA[jm] = *(const us4*)(Mrowa + j0 + 16 * jm + 4 * lg);
      mvB[jm] = *(const us4*)(Mrowb + j0 + 16 * jm + 4 * lg);
    }
    __builtin_amdgcn_sched_barrier(0);
    if (t < 16) {
      int nb = ((t + 1) & 1) << 10;
      size_t ko = (size_t)(t + 1) * 4096;   // K advances 64 rows * 64 elems
      int vo = (t + 1) * 64;                // V^T advances 64 columns
      gload16(kS0 + ko, smem + nb + tid);
      gload16(kS1 + ko, smem + nb + tid + 256);
      gload16(vS0 + vo, smem + nb + 512 + tid);
      gload16(vS1 + vo, smem + nb + 512 + tid + 256);
    }
    __builtin_amdgcn_sched_barrier(0);
    const bfrag* LK = (const bfrag*)(smem + cb);
    const char*  LVc = (const char*)(smem + cb + 512);

    // --- K fragments (shared by both sub-blocks) ---
    bfrag ka[4], kb2[4];
#pragma unroll
    for (int jm = 0; jm < 4; jm++) {
      int row = jm * 16 + lm;
      ka[jm]  = LK[row * 8 + ((0 + lg) ^ (row & 7))];
      kb2[jm] = LK[row * 8 + ((4 + lg) ^ (row & 7))];
    }
    // --- QK^T both sub-blocks (16x16x32) ---
    ffrag sa[4], sb[4];
    __builtin_amdgcn_s_setprio(1);
#pragma unroll
    for (int jm = 0; jm < 4; jm++) {
      ffrag a = zero4;
      a = MFMA16(ka[jm], qa0, a);
      a = MFMA16(kb2[jm], qa1, a);
      sa[jm] = a;
      ffrag bb = zero4;
      bb = MFMA16(ka[jm], qb0, bb);
      bb = MFMA16(kb2[jm], qb1, bb);
      sb[jm] = bb;
    }
    __builtin_amdgcn_s_setprio(0);

    // --- V B-fragments for 16x16x16 PV (shared by a,b) ---
    bfrag4 vf[4][4];
#pragma unroll
    for (int jm = 0; jm < 4; jm++)
#pragma unroll
      for (int dm = 0; dm < 4; dm++) {
        int vrow = dm * 16 + lm;
        union { uint2 u; bfrag4 b; } cu;
        cu.u = *(const uint2*)(LVc + vrow * 128 +
                               ((((jm << 1) | (lg >> 1)) ^ (vrow & 7)) << 4) + 8 * (lg & 1));
        vf[jm][dm] = cu.b;
      }

    // --- softmax -> PV A-fragments, all in registers ---
    bfrag4 paA[4], paB[4];
#pragma unroll
    for (int jm = 0; jm < 4; jm++) {
      float p0 = EXP2(sa[jm][0]), p1 = EXP2(sa[jm][1]), p2 = EXP2(sa[jm][2]), p3 = EXP2(sa[jm][3]);
      float q0 = p0 * bf2f(mvA[jm][0]), q1 = p1 * bf2f(mvA[jm][1]);
      float q2 = p2 * bf2f(mvA[jm][2]), q3 = p3 * bf2f(mvA[jm][3]);
      TpA += (q0 + q1) + (q2 + q3);
      union { uint2 u; bfrag4 b; } cv;
      cv.u.x = pkbf(q0, q1); cv.u.y = pkbf(q2, q3);
      paA[jm] = cv.b;
    }
#pragma unroll
    for (int jm = 0; jm < 4; jm++) {
      float p0 = EXP2(sb[jm][0]), p1 = EXP2(sb[jm][1]), p2 = EXP2(sb[jm][2]), p3 = EXP2(sb[jm][3]);
      float q0 = p0 * bf2f(mvB[jm][0]), q1 = p1 * bf2f(mvB[jm][1]);
      float q2 = p2 * bf2f(mvB[jm][2]), q3 = p3 * bf2f(mvB[jm][3]);
      TpB += (q0 + q1) + (q2 + q3);
      union { uint2 u; bfrag4 b; } cv;
      cv.u.x = pkbf(q0, q1); cv.u.y = pkbf(q2, q3);
      paB[jm] = cv.b;
    }

    // --- PV: 16x16x16, pure register operands; a/b interleaved for ILP ---
    __builtin_amdgcn_s_setprio(1);
#pragma unroll
    for (int jm = 0; jm < 4; jm++)
#pragma unroll
      for (int dm = 0; dm < 4; dm++) {
        oaccA[dm] = MFMA16K16(paA[jm], vf[jm][dm], oaccA[dm]);
        oaccB[dm] = MFMA16K16(paB[jm], vf[jm][dm], oaccB[dm]);
      }
    __builtin_amdgcn_s_setprio(0);

    // next tile's K/V landed; all waves done reading current buffers.
    asm volatile("s_waitcnt vmcnt(0)" ::: "memory");
    __builtin_amdgcn_sched_barrier(0);
    __builtin_amdgcn_s_barrier();
  }
  // --- finalize ---
  TpA += __shfl_xor(TpA, 16); TpA += __shfl_xor(TpA, 32);
  TpB += __shfl_xor(TpB, 16); TpB += __shfl_xor(TpB, 32);
  float dnA_row = 1.f / TpA;   // eps*Z term dropped (rel err ~2e-6)
  float dnB_row = 1.f / TpB;
  float dnA[4], dnB[4];
#pragma unroll
  for (int r = 0; r < 4; r++) { dnA[r] = __shfl(dnA_row, 4 * lg + r); dnB[r] = __shfl(dnB_row, 4 * lg + r); }
#pragma unroll
  for (int dm = 0; dm < 4; dm++)
#pragma unroll
    for (int r = 0; r < 4; r++) {
      int ia = i0a + 4 * lg + r;
      if (ia < Nn) Og[((size_t)(b * Nn + ia)) * Dd + h * 64 + dm * 16 + lm] = f2bf(oaccA[dm][r] * dnA[r]);
      int ibr = i0b + 4 * lg + r;
      if (ibr < Nn) Og[((size_t)(b * Nn + ibr)) * Dd + h * 64 + dm * 16 + lm] = f2bf(oaccB[dm][r] * dnB[r]);
    }
}

// ---------------- launch ----------------
extern "C" void kernel_launch(void* const* d_in, const int* in_sizes, int n_in,
                              void* d_out, int out_size, void* d_ws, size_t ws_size,
                              hipStream_t stream) {
  const float* x      = (const float*)d_in[0];
  const float* graph  = (const float*)d_in[1];
  const float* transf = (const float*)d_in[2];
  const float* Wqkv   = (const float*)d_in[3];
  const float* bqkv   = (const float*)d_in[4];
  const float* Wproj  = (const float*)d_in[5];
  const float* bproj  = (const float*)d_in[6];
  float* out = (float*)d_out;
  char* ws = (char*)d_ws;

  unsigned short* xbf  = (unsigned short*)(ws + 0);                 // 12,595,200 (also attn_out)
  unsigned short* wqb  = (unsigned short*)(ws + 12595200);          //  3,538,944
  unsigned short* wpb  = (unsigned short*)(ws + 16134144);          //  1,179,648
  unsigned short* Qb   = (unsigned short*)(ws + 17313792);          // 13,369,344
  unsigned short* Kb   = (unsigned short*)(ws + 30683136);          // 13,369,344
  unsigned short* Vb   = (unsigned short*)(ws + 44052480);          // 13,369,344
  float*          pw   = (float*)(ws + 57421824);                   //     32,768
  unsigned short* mask = (unsigned short*)(ws + 57454592);          // 18,939,904
  unsigned short* aob  = xbf;  // attention output bf16 [8200][768]

  prep_kernel<<<2152, 256, 0, stream>>>(x, xbf, (MROWS * Dd) / 4,
                                        Wqkv, wqb, (3 * Dd * Dd) / 4,
                                        Wproj, wpb, (Dd * Dd) / 4,
                                        Qb, Kb, Vb, transf, pw);
  mask_kernel<<<dim3(NP, Bq), 256, 0, stream>>>(graph, pw, mask);
  qkv_gemm_kernel<<<65 * 18, 256, 0, stream>>>(xbf, wqb, bqkv, Qb, Kb, Vb);
  attn_kernel<<<864, 256, 0, stream>>>(Qb, Kb, Vb, mask, aob);
  proj_gemm_kernel<<<65 * 6, 256, 0, stream>>>(aob, wpb, bproj, out);
}